// Round 21
// baseline (64.665 us; speedup 1.0000x reference)
//
#include <hip/hip_runtime.h>
#include <math.h>

// Problem constants
#define BB 16384
#define TT 99
#define RR 10
#define LL 3

// DPP cross-lane (VALU pipe):
// QP(v,j): every lane of a 4-lane quad gets quad-lane j's value (verified R15+).
// ROR4(v): rotate within each 16-lane row by 4 (direction resolved by probe).
#define QP(v, j) __int_as_float(__builtin_amdgcn_mov_dpp(                     \
    __float_as_int(v), (j) * 0x55, 0xF, 0xF, true))
#define ROR4(v)  __int_as_float(__builtin_amdgcn_mov_dpp(                     \
    __float_as_int(v), 0x124, 0xF, 0xF, true))

// 16-lane all-gather: 3 rotations + 16 quad_perms = 19 DPP ops, pure VALU.
// Slot k of lane l carries SOME unit of the 16-group -- which one is
// determined at runtime by probing this exact network with the lane index.
__device__ __forceinline__ void gather16(float v0, float (&hg)[16]) {
    const float v1 = ROR4(v0);
    const float v2 = ROR4(v1);
    const float v3 = ROR4(v2);
    hg[ 0] = QP(v0, 0); hg[ 1] = QP(v0, 1); hg[ 2] = QP(v0, 2); hg[ 3] = QP(v0, 3);
    hg[ 4] = QP(v1, 0); hg[ 5] = QP(v1, 1); hg[ 6] = QP(v1, 2); hg[ 7] = QP(v1, 3);
    hg[ 8] = QP(v2, 0); hg[ 9] = QP(v2, 1); hg[10] = QP(v2, 2); hg[11] = QP(v2, 3);
    hg[12] = QP(v3, 0); hg[13] = QP(v3, 1); hg[14] = QP(v3, 2); hg[15] = QP(v3, 3);
}

// One 32-step (or 3-step tail) section: pure register loop, stores at
// compile-time immediate offsets. One unit per lane; coefficients for dummy
// slots are 0.0 so the 16-FMA dot is mapping-agnostic.
template <int TB, int N>
__device__ __forceinline__ void rnn_section(
    uint64_t wq, float& ho, const float (&UA)[16],
    float cA1, float cA2, bool owner, float* __restrict__ outp)
{
#pragma unroll
    for (int u = 0; u < N; ++u) {
        const int sel = (int)(wq & 3);
        wq >>= 2;

        float hg[16];
        gather16(ho, hg);

        float a0 = (sel == 1) ? cA1 : cA2;
        float a1 = 0.0f;
#pragma unroll
        for (int i = 0; i < 8; ++i) {          // split chains: 2x8 FMA deep
            a0 = fmaf(hg[i],     UA[i],     a0);
            a1 = fmaf(hg[8 + i], UA[8 + i], a1);
        }
        const float e  = __expf(2.0f * (a0 + a1));
        const float hn = fmaf(-2.0f, __builtin_amdgcn_rcpf(e + 1.0f), 1.0f);
        if (sel != 0) ho = hn;                 // Keras masking: carry h

        if (owner) outp[(TB + u) * RR] = ho;   // lanes 0..9 of each 16-group
    }
}

// ===================== K1: recurrence -> states (direct) =====================
// R21: 16 LANES PER ROW -> 4096 waves = 16 waves/CU = 4 waves/SIMD. The
// 49-50us plateau across R12-R20 tracks 2-way chain concurrency per SIMD
// (2048 waves); doubling waves doubles chains in flight, filling the
// dependent-chain latency that VALUBusy=44% shows is exposed.
// Zero memory ops in the step loop (2-bit token codes in four u64 regs).
__global__ __launch_bounds__(256, 4)
void rnn_seq_kernel(const int* __restrict__ tok_ids,
                    const float* __restrict__ emb,
                    const float* __restrict__ W,
                    const float* __restrict__ U,
                    const float* __restrict__ bvec,
                    float* __restrict__ states_out)
{
    __shared__ unsigned char s_tk[16 * 100];  // 1.6 KB: token byte per (row,t)

    const int tid  = threadIdx.x;
    const int l    = tid & 63;
    const int wv   = tid >> 6;                // wave in block (0..3)
    const int gl   = l & 15;                  // lane in 16-group
    const int rowl = wv * 4 + (l >> 4);       // row within block (0..15)
    const int row  = blockIdx.x * 16 + rowl;

    // ---- stage tokens for the block's 16 rows (coalesced) ----
#pragma unroll
    for (int i = 0; i < 7; ++i) {
        const int p = tid + 256 * i;
        if (p < 16 * TT) {
            const int r = p / TT;             // compile-time divisor
            s_tk[r * 100 + (p - r * TT)] =
                (unsigned char)tok_ids[(size_t)blockIdx.x * (16 * TT) + p];
        }
    }
    __syncthreads();                          // staging crosses waves now

    // ---- pack own row's 99 token codes into 4 u64 registers (2 bits/step) ----
    const uint32_t* tp = reinterpret_cast<const uint32_t*>(&s_tk[rowl * 100]);
    uint64_t w0 = 0, w1 = 0, w2 = 0, w3 = 0;
#pragma unroll
    for (int t = 0; t < 32; ++t)
        w0 |= (uint64_t)((tp[t >> 2] >> (8 * (t & 3))) & 3) << (2 * t);
#pragma unroll
    for (int t = 32; t < 64; ++t)
        w1 |= (uint64_t)((tp[t >> 2] >> (8 * (t & 3))) & 3) << (2 * (t - 32));
#pragma unroll
    for (int t = 64; t < 96; ++t)
        w2 |= (uint64_t)((tp[t >> 2] >> (8 * (t & 3))) & 3) << (2 * (t - 64));
#pragma unroll
    for (int t = 96; t < 99; ++t)
        w3 |= (uint64_t)((tp[t >> 2] >> (8 * (t & 3))) & 3) << (2 * (t - 96));

    // ---- probe the gather network: slot k <- which source lane/unit? ----
    float pg[16];
    gather16((float)gl, pg);
    const int jA = (gl < 10) ? gl : 9;        // dummy lanes: clamp (unused)
    float UA[16];
#pragma unroll
    for (int k = 0; k < 16; ++k) {
        const int ui = (int)pg[k];
        UA[k] = (ui < 10) ? U[ui * RR + jA] : 0.0f;   // dummy slots: 0-coeff
    }

    float cA1 = bvec[jA], cA2 = cA1;
#pragma unroll
    for (int i = 0; i < RR; ++i) {
        const float wA = W[i * RR + jA];
        cA1 = fmaf(emb[RR + i],     wA, cA1); // token-1 row
        cA2 = fmaf(emb[2 * RR + i], wA, cA2); // token-2 row
    }

    const bool owner = (gl < 10);
    float* outp = states_out + (size_t)row * (TT * RR) + jA;  // jA==gl for owners
    float ho = 0.0f;

    rnn_section< 0, 32>(w0, ho, UA, cA1, cA2, owner, outp);
    rnn_section<32, 32>(w1, ho, UA, cA1, cA2, owner, outp);
    rnn_section<64, 32>(w2, ho, UA, cA1, cA2, owner, outp);
    rnn_section<96,  3>(w3, ho, UA, cA1, cA2, owner, outp);
}

// ===================== K2: epilogue (full occupancy) =====================
__global__ __launch_bounds__(256)
void epilogue_kernel(const float* __restrict__ states,
                     const float* __restrict__ labels,
                     const float* __restrict__ Wo,
                     const float* __restrict__ bo,
                     float* __restrict__ probs_out,
                     float* __restrict__ ws)
{
    const int NT     = BB * TT;               // 1,622,016
    const int tid    = blockIdx.x * 256 + threadIdx.x;
    const int stride = 2048 * 256;

    float Wc0[RR], Wc1[RR], Wc2[RR];
#pragma unroll
    for (int j = 0; j < RR; ++j) {
        Wc0[j] = Wo[j * LL + 0];
        Wc1[j] = Wo[j * LL + 1];
        Wc2[j] = Wo[j * LL + 2];
    }
    const float b0 = bo[0], b1 = bo[1], b2 = bo[2];

    float loss = 0.0f;
    int   corr = 0;

#pragma unroll 1
    for (int idx = tid; idx < NT; idx += stride) {
        const float* hp = states + (size_t)idx * RR;   // 8B-aligned (40B stride)
        float h[RR];
#pragma unroll
        for (int j = 0; j < RR; j += 2) {
            const float2 v = *reinterpret_cast<const float2*>(hp + j);
            h[j] = v.x; h[j + 1] = v.y;
        }
        const float la1 = labels[(size_t)idx * LL + 1];
        const float la2 = labels[(size_t)idx * LL + 2];
        const int   y   = (la1 > 0.5f) ? 1 : ((la2 > 0.5f) ? 2 : 0);

        float l0 = b0, l1 = b1, l2 = b2;
#pragma unroll
        for (int j = 0; j < RR; ++j) {
            l0 = fmaf(h[j], Wc0[j], l0);
            l1 = fmaf(h[j], Wc1[j], l1);
            l2 = fmaf(h[j], Wc2[j], l2);
        }
        const float e0 = __expf(l0), e1 = __expf(l1), e2 = __expf(l2);
        const float S  = e0 + e1 + e2;
        const float rs = __builtin_amdgcn_rcpf(S);
        probs_out[(size_t)idx * LL + 0] = e0 * rs;
        probs_out[(size_t)idx * LL + 1] = e1 * rs;
        probs_out[(size_t)idx * LL + 2] = e2 * rs;

        // loss: -log(clip(p_y, 1e-7, 1)) == min(logS - l_y, -log(1e-7))
        const float ly = (y == 0) ? l0 : ((y == 1) ? l1 : l2);
        loss += fminf(__logf(S) - ly, 16.11809565f);

        // accuracy: argmax(logits) == argmax(probs) (monotonic, same ties)
        int ap = 0; float pm = l0;
        if (l1 > pm) { ap = 1; pm = l1; }
        if (l2 > pm) { ap = 2; }
        corr += (ap == y) ? 1 : 0;
    }

    __shared__ float sl[4], sc[4];
    float ls = loss, cs = (float)corr;
#pragma unroll
    for (int off = 32; off > 0; off >>= 1) {
        ls += __shfl_down(ls, off, 64);
        cs += __shfl_down(cs, off, 64);
    }
    if ((threadIdx.x & 63) == 0) { sl[threadIdx.x >> 6] = ls; sc[threadIdx.x >> 6] = cs; }
    __syncthreads();
    if (threadIdx.x == 0) {
        ws[blockIdx.x]        = sl[0] + sl[1] + sl[2] + sl[3];
        ws[2048 + blockIdx.x] = sc[0] + sc[1] + sc[2] + sc[3];
    }
}

__global__ __launch_bounds__(256)
void finalize_kernel(const float* __restrict__ ws, float* __restrict__ out_tail)
{
    __shared__ float sl[4], sc[4];
    const int t = threadIdx.x;
    float ls = 0.0f, cs = 0.0f;
#pragma unroll
    for (int i = 0; i < 8; ++i) {
        ls += ws[t + 256 * i];
        cs += ws[2048 + t + 256 * i];
    }
#pragma unroll
    for (int off = 32; off > 0; off >>= 1) {
        ls += __shfl_down(ls, off, 64);
        cs += __shfl_down(cs, off, 64);
    }
    if ((t & 63) == 0) { sl[t >> 6] = ls; sc[t >> 6] = cs; }
    __syncthreads();
    if (t == 0) {
        const float L = sl[0] + sl[1] + sl[2] + sl[3];
        const float C = sc[0] + sc[1] + sc[2] + sc[3];
        const float inv = 1.0f / (float)((size_t)BB * TT);
        out_tail[0] = C * inv;   // accuracy
        out_tail[1] = L * inv;   // loss
    }
}

extern "C" void kernel_launch(void* const* d_in, const int* in_sizes, int n_in,
                              void* d_out, int out_size, void* d_ws, size_t ws_size,
                              hipStream_t stream)
{
    const int*   tok    = (const int*)  d_in[0];
    const float* labels = (const float*)d_in[1];
    // d_in[2] = mask (unused by reference math)
    const float* emb = (const float*)d_in[3];
    const float* W   = (const float*)d_in[4];
    const float* U   = (const float*)d_in[5];
    const float* bv  = (const float*)d_in[6];
    const float* Wo  = (const float*)d_in[7];
    const float* bo  = (const float*)d_in[8];

    float* out    = (float*)d_out;
    float* states = out;                                  // [B,T,10]
    float* probs  = out + (size_t)BB * TT * RR;           // [B,T,3]
    float* tail   = out + (size_t)BB * TT * (RR + LL);    // accuracy, loss
    float* ws     = (float*)d_ws;                         // 4096 floats used

    rnn_seq_kernel<<<BB / 16, 256, 0, stream>>>(tok, emb, W, U, bv, states);
    epilogue_kernel<<<2048, 256, 0, stream>>>(states, labels, Wo, bo, probs, ws);
    finalize_kernel<<<1, 256, 0, stream>>>(ws, tail);
}

// Round 22
// 57.438 us; speedup vs baseline: 1.1258x; 1.1258x over previous
//
#include <hip/hip_runtime.h>
#include <math.h>

// Problem constants
#define BB 16384
#define TT 99
#define RR 10
#define LL 3

// DPP cross-lane (VALU pipe):
// QP(v,j): every lane of a 4-lane quad gets quad-lane j's value.
// HMIR(v): mirror within each 8-lane half-row (lane g <-> 7-g).
#define QP(v, j) __int_as_float(__builtin_amdgcn_mov_dpp(                     \
    __float_as_int(v), (j) * 0x55, 0xF, 0xF, true))
#define HMIR(v)  __int_as_float(__builtin_amdgcn_mov_dpp(                     \
    __float_as_int(v), 0x141, 0xF, 0xF, true))

// 8-lane full-h gather: 11 DPP ops (verified R15/R18).
__device__ __forceinline__ void gather10(float hoA, float hoB, float (&hg)[RR]) {
    hg[0] = QP(hoA, 0); hg[1] = QP(hoA, 1);
    hg[2] = QP(hoA, 2); hg[3] = QP(hoA, 3);
    const float mr = HMIR(hoA);
    hg[4] = QP(mr, 0);  hg[5] = QP(mr, 1);
    hg[6] = QP(mr, 2);  hg[7] = QP(mr, 3);
    hg[8] = QP(hoB, 0); hg[9] = QP(hoB, 1);
}

// Per-step epilogue for step `tep` (compile-time under unroll), using
// hg = h_tep (permuted order; Wc permuted identically). Each lane computes
// ONE logit (lane g&3 -> class min(g&3,2)); the 3 exponentials are shared
// intra-quad via QP; probs stored by lanes g<3; loss/acc on lane g==0.
__device__ __forceinline__ void epi_step(
    const float (&hg)[RR], int yv, int tep, int g,
    const float (&Wc)[RR], float boc,
    float* __restrict__ prow, float& loss, int& corr)
{
    float lg = boc;
#pragma unroll
    for (int i = 0; i < RR; ++i) lg = fmaf(hg[i], Wc[i], lg);
    const float eo = __expf(lg);
    const float e0 = QP(eo, 0), e1 = QP(eo, 1), e2 = QP(eo, 2);
    const float S  = e0 + e1 + e2;
    const float rs = __builtin_amdgcn_rcpf(S);
    if (g < 3) prow[tep * LL + g] = eo * rs;     // p_g, 3 lanes of quad0

    const float ey = (yv == 0) ? e0 : ((yv == 1) ? e1 : e2);
    const float py = fmaxf(ey * rs, 1e-7f);      // clip low; py<=1 always
    const float lt = -__logf(py);                // <= 16.118 automatically

    int ap = 0; float pm = e0;                   // argmax(probs)==argmax(e)
    if (e1 > pm) { ap = 1; pm = e1; }
    if (e2 > pm) { ap = 2; }
    if (g == 0) { loss += lt; corr += (ap == yv) ? 1 : 0; }
}

// One section of the recurrence, fully unrolled; all offsets compile-time.
// PIPELINE SKEW: iteration t's gather (h_{t-1}) feeds the epilogue for step
// t-1, then the recurrence computes h_t. y-packs are slot-shifted by +1 so
// the extraction at iteration t yields y_{t-1}.
template <int TB, int N>
__device__ __forceinline__ void rnn_section(
    uint64_t wsel, uint64_t wy, float& hoA, float& hoB,
    const float (&UA)[RR], const float (&UB)[RR],
    const float (&Wc)[RR], float boc,
    float cA1, float cA2, float cB1, float cB2,
    float* __restrict__ outA, float* __restrict__ outB,
    float* __restrict__ prow, int g, float& loss, int& corr)
{
#pragma unroll
    for (int u = 0; u < N; ++u) {
        const int sel = (int)(wsel & 3); wsel >>= 2;
        const int yv  = (int)(wy & 3);   wy >>= 2;   // y for step TB+u-1

        float hg[RR];
        gather10(hoA, hoB, hg);                      // h_{t-1}

        if (TB + u > 0)                              // folds at unroll time
            epi_step(hg, yv, TB + u - 1, g, Wc, boc, prow, loss, corr);

        const bool is1 = (sel == 1);
        float aA0 = is1 ? cA1 : cA2, aB0 = is1 ? cB1 : cB2;
        float aA1 = 0.0f, aB1 = 0.0f;
#pragma unroll
        for (int i = 0; i < 5; ++i) {                // split chains: 2x5 deep
            aA0 = fmaf(hg[i],     UA[i],     aA0);
            aA1 = fmaf(hg[5 + i], UA[5 + i], aA1);
            aB0 = fmaf(hg[i],     UB[i],     aB0);
            aB1 = fmaf(hg[5 + i], UB[5 + i], aB1);
        }
        // tanh pair, shared rcp (3 trans)
        const float eA = __expf(2.0f * (aA0 + aA1));
        const float eB = __expf(2.0f * (aB0 + aB1));
        const float pA = eA + 1.0f, pB = eB + 1.0f;
        const float r  = __builtin_amdgcn_rcpf(pA * pB);
        const float hnA = fmaf(-2.0f * pB, r, 1.0f);
        const float hnB = fmaf(-2.0f * pA, r, 1.0f);
        if (sel != 0) { hoA = hnA; hoB = hnB; }      // Keras masking: carry h

        outA[(TB + u) * RR] = hoA;                   // imm offsets <= 3920B
        outB[(TB + u) * RR] = hoB;
    }
}

// =============== K1: fused recurrence + per-step epilogue ===============
// R22 = R18's K1 (DPP gather, register-packed codes, direct stores) with
// the ENTIRE epilogue fused per-step: every lane already holds full h in
// hg[] each step, so dense+softmax+probs+loss ride along (~31 instrs that
// sit OFF the recurrence chain -> fill its stall slots). K2 (17-20us of
// memory-bound re-read) and its launch disappear. 512x256 = 2048 waves.
__global__ __launch_bounds__(256, 2)
void rnn_fused_kernel(const int* __restrict__ tok_ids,
                      const float* __restrict__ labels,
                      const float* __restrict__ emb,
                      const float* __restrict__ W,
                      const float* __restrict__ U,
                      const float* __restrict__ bvec,
                      const float* __restrict__ Wo,
                      const float* __restrict__ bo,
                      float* __restrict__ states_out,
                      float* __restrict__ probs_out,
                      float* __restrict__ ws)
{
    __shared__ unsigned char s_code[4][8 * 100];  // (sel<<2)|y per (row,t)

    const int tid = threadIdx.x;
    const int w   = tid >> 6;
    const int l   = tid & 63;
    const int r8  = l >> 3;                   // row within wave (0..7)
    const int g   = l & 7;                    // unit slot (0..7)
    const int rowbase = blockIdx.x * 32 + w * 8;

    // ---- preamble: classify tokens+labels -> code bytes (coalesced) ----
#pragma unroll
    for (int i = 0; i < 13; ++i) {
        const int p = l + 64 * i;
        if (p < 8 * TT) {
            const size_t gi = (size_t)rowbase * TT + p;
            const int   tk  = tok_ids[gi];
            const float la1 = labels[gi * LL + 1];
            const float la2 = labels[gi * LL + 2];
            const int   y   = (la1 > 0.5f) ? 1 : ((la2 > 0.5f) ? 2 : 0);
            const int   r   = p / TT;         // compile-time divisor
            s_code[w][r * 100 + (p - r * TT)] = (unsigned char)((tk << 2) | y);
        }
    }

    // ---- pack own row: sel at slot t, y at slot t+1 (pipeline skew) ----
    const unsigned char* cp = &s_code[w][r8 * 100];
    uint64_t sw0 = 0, sw1 = 0, sw2 = 0, sw3 = 0;
    uint64_t yw0 = 0, yw1 = 0, yw2 = 0, yw3 = 0;
#pragma unroll
    for (int t = 0; t < TT; ++t) {
        const uint64_t c  = (uint64_t)cp[t];
        const uint64_t sv = (c >> 2) & 3, yv = c & 3;
        if (t < 32)              sw0 |= sv << (2 * t);
        else if (t < 64)         sw1 |= sv << (2 * (t - 32));
        else if (t < 96)         sw2 |= sv << (2 * (t - 64));
        else                     sw3 |= sv << (2 * (t - 96));
        const int s2 = t + 1;
        if (s2 < 32)             yw0 |= yv << (2 * s2);
        else if (s2 < 64)        yw1 |= yv << (2 * (s2 - 32));
        else if (s2 < 96)        yw2 |= yv << (2 * (s2 - 64));
        else                     yw3 |= yv << (2 * (s2 - 96));
    }
    const int y98 = (int)((yw3 >> 6) & 3);    // slot 99 = step 98

    // ---- per-lane gather order (quad-dependent) + weight coefficients ----
    const int qpar = g >> 2;
    int ord[8];
#pragma unroll
    for (int j = 0; j < 4; ++j) {
        ord[j]     = qpar ? 4 + j : j;
        ord[4 + j] = qpar ? 3 - j : 7 - j;
    }
    const int jA = g;
    const int jB = ((g & 3) < 2) ? 8 + (g & 3) : 8;
    const int gc = ((g & 3) < 2) ? (g & 3) : 2;    // this lane's logit class

    float UA[RR], UB[RR], Wc[RR];
#pragma unroll
    for (int k2 = 0; k2 < 8; ++k2) {
        UA[k2] = U[ord[k2] * RR + jA];
        UB[k2] = U[ord[k2] * RR + jB];
        Wc[k2] = Wo[ord[k2] * LL + gc];            // same permutation as hg
    }
    UA[8] = U[8 * RR + jA]; UA[9] = U[9 * RR + jA];
    UB[8] = U[8 * RR + jB]; UB[9] = U[9 * RR + jB];
    Wc[8] = Wo[8 * LL + gc]; Wc[9] = Wo[9 * LL + gc];
    const float boc = bo[gc];

    float cA1 = bvec[jA], cA2 = cA1, cB1 = bvec[jB], cB2 = cB1;
#pragma unroll
    for (int i = 0; i < RR; ++i) {
        const float e1 = emb[RR + i];          // token-1 row
        const float e2 = emb[2 * RR + i];      // token-2 row
        const float wA = W[i * RR + jA];
        const float wB = W[i * RR + jB];
        cA1 = fmaf(e1, wA, cA1); cA2 = fmaf(e2, wA, cA2);
        cB1 = fmaf(e1, wB, cB1); cB2 = fmaf(e2, wB, cB2);
    }

    const int row = rowbase + r8;
    float* outA = states_out + (size_t)row * (TT * RR) + jA;
    float* outB = states_out + (size_t)row * (TT * RR) + jB;
    float* prow = probs_out  + (size_t)row * (TT * LL);

    float hoA = 0.0f, hoB = 0.0f;
    float loss = 0.0f;
    int   corr = 0;

    rnn_section< 0, 32>(sw0, yw0, hoA, hoB, UA, UB, Wc, boc,
                        cA1, cA2, cB1, cB2, outA, outB, prow, g, loss, corr);
    rnn_section<32, 32>(sw1, yw1, hoA, hoB, UA, UB, Wc, boc,
                        cA1, cA2, cB1, cB2, outA, outB, prow, g, loss, corr);
    rnn_section<64, 32>(sw2, yw2, hoA, hoB, UA, UB, Wc, boc,
                        cA1, cA2, cB1, cB2, outA, outB, prow, g, loss, corr);
    rnn_section<96,  3>(sw3, yw3, hoA, hoB, UA, UB, Wc, boc,
                        cA1, cA2, cB1, cB2, outA, outB, prow, g, loss, corr);

    // ---- final epilogue for step 98 (h_98 is in hoA/hoB) ----
    {
        float hg[RR];
        gather10(hoA, hoB, hg);
        epi_step(hg, y98, 98, g, Wc, boc, prow, loss, corr);
    }

    // ---- wave reduction -> one partial per wave (deterministic) ----
    float ls = loss, cs = (float)corr;
#pragma unroll
    for (int off = 32; off > 0; off >>= 1) {
        ls += __shfl_down(ls, off, 64);
        cs += __shfl_down(cs, off, 64);
    }
    if (l == 0) {
        const int wid = blockIdx.x * 4 + w;   // 0..2047
        ws[wid]        = ls;
        ws[2048 + wid] = cs;
    }
}

__global__ __launch_bounds__(256)
void finalize_kernel(const float* __restrict__ ws, float* __restrict__ out_tail)
{
    __shared__ float sl[4], sc[4];
    const int t = threadIdx.x;
    float ls = 0.0f, cs = 0.0f;
#pragma unroll
    for (int i = 0; i < 8; ++i) {
        ls += ws[t + 256 * i];
        cs += ws[2048 + t + 256 * i];
    }
#pragma unroll
    for (int off = 32; off > 0; off >>= 1) {
        ls += __shfl_down(ls, off, 64);
        cs += __shfl_down(cs, off, 64);
    }
    if ((t & 63) == 0) { sl[t >> 6] = ls; sc[t >> 6] = cs; }
    __syncthreads();
    if (t == 0) {
        const float L = sl[0] + sl[1] + sl[2] + sl[3];
        const float C = sc[0] + sc[1] + sc[2] + sc[3];
        const float inv = 1.0f / (float)((size_t)BB * TT);
        out_tail[0] = C * inv;   // accuracy
        out_tail[1] = L * inv;   // loss
    }
}

extern "C" void kernel_launch(void* const* d_in, const int* in_sizes, int n_in,
                              void* d_out, int out_size, void* d_ws, size_t ws_size,
                              hipStream_t stream)
{
    const int*   tok    = (const int*)  d_in[0];
    const float* labels = (const float*)d_in[1];
    // d_in[2] = mask (unused by reference math)
    const float* emb = (const float*)d_in[3];
    const float* W   = (const float*)d_in[4];
    const float* U   = (const float*)d_in[5];
    const float* bv  = (const float*)d_in[6];
    const float* Wo  = (const float*)d_in[7];
    const float* bo  = (const float*)d_in[8];

    float* out    = (float*)d_out;
    float* states = out;                                  // [B,T,10]
    float* probs  = out + (size_t)BB * TT * RR;           // [B,T,3]
    float* tail   = out + (size_t)BB * TT * (RR + LL);    // accuracy, loss
    float* ws     = (float*)d_ws;                         // 4096 floats used

    rnn_fused_kernel<<<BB / 32, 256, 0, stream>>>(tok, labels, emb, W, U, bv,
                                                  Wo, bo, states, probs, ws);
    finalize_kernel<<<1, 256, 0, stream>>>(ws, tail);
}

// Round 23
// 52.981 us; speedup vs baseline: 1.2205x; 1.0841x over previous
//
#include <hip/hip_runtime.h>
#include <math.h>

// Problem constants
#define BB 16384
#define TT 99
#define RR 10
#define LL 3

// DPP cross-lane (VALU pipe):
// QP(v,j): every lane of a 4-lane quad gets quad-lane j's value.
// HMIR(v): mirror within each 8-lane half-row (lane g <-> 7-g).
#define QP(v, j) __int_as_float(__builtin_amdgcn_mov_dpp(                     \
    __float_as_int(v), (j) * 0x55, 0xF, 0xF, true))
#define HMIR(v)  __int_as_float(__builtin_amdgcn_mov_dpp(                     \
    __float_as_int(v), 0x141, 0xF, 0xF, true))

// 8-lane full-h gather: 11 DPP ops (verified R15+).
__device__ __forceinline__ void gather10(float hoA, float hoB, float (&hg)[RR]) {
    hg[0] = QP(hoA, 0); hg[1] = QP(hoA, 1);
    hg[2] = QP(hoA, 2); hg[3] = QP(hoA, 3);
    const float mr = HMIR(hoA);
    hg[4] = QP(mr, 0);  hg[5] = QP(mr, 1);
    hg[6] = QP(mr, 2);  hg[7] = QP(mr, 3);
    hg[8] = QP(hoB, 0); hg[9] = QP(hoB, 1);
}

// Linear epilogue for step tep: ONE logit per lane (10 FMA, ZERO trans --
// R22's regression came from 3 extra trans/step). Lane 0 embeds the label
// class y in l0's low 2 mantissa bits (<=2ulp, vs 0.022 threshold). Lanes
// g<3 store their logit to the probs buffer (K2 softmaxes in place).
__device__ __forceinline__ void logit_step(
    const float (&hg)[RR], int yv, int tep, int g,
    const float (&Wc)[RR], float boc, float* __restrict__ prow)
{
    float lg = boc;
#pragma unroll
    for (int i = 0; i < RR; ++i) lg = fmaf(hg[i], Wc[i], lg);
    if (g == 0) lg = __int_as_float((__float_as_int(lg) & ~3) | yv);
    if (g < 3) prow[tep * LL + g] = lg;
}

// One section of the recurrence, fully unrolled; all offsets compile-time.
// PIPELINE SKEW (verified R22): iteration t's gather (h_{t-1}) feeds the
// logits for step t-1, then the recurrence computes h_t. y-packs are
// slot-shifted by +1 so extraction at iteration t yields y_{t-1}.
template <int TB, int N>
__device__ __forceinline__ void rnn_section(
    uint64_t wsel, uint64_t wy, float& hoA, float& hoB,
    const float (&UA)[RR], const float (&UB)[RR],
    const float (&Wc)[RR], float boc,
    float cA1, float cA2, float cB1, float cB2,
    float* __restrict__ outA, float* __restrict__ outB,
    float* __restrict__ prow, int g)
{
#pragma unroll
    for (int u = 0; u < N; ++u) {
        const int sel = (int)(wsel & 3); wsel >>= 2;
        const int yv  = (int)(wy & 3);   wy >>= 2;   // y for step TB+u-1

        float hg[RR];
        gather10(hoA, hoB, hg);                      // h_{t-1}

        if (TB + u > 0)                              // folds at unroll time
            logit_step(hg, yv, TB + u - 1, g, Wc, boc, prow);

        const bool is1 = (sel == 1);
        float aA0 = is1 ? cA1 : cA2, aB0 = is1 ? cB1 : cB2;
        float aA1 = 0.0f, aB1 = 0.0f;
#pragma unroll
        for (int i = 0; i < 5; ++i) {                // split chains: 2x5 deep
            aA0 = fmaf(hg[i],     UA[i],     aA0);
            aA1 = fmaf(hg[5 + i], UA[5 + i], aA1);
            aB0 = fmaf(hg[i],     UB[i],     aB0);
            aB1 = fmaf(hg[5 + i], UB[5 + i], aB1);
        }
        // tanh pair, shared rcp (3 trans)
        const float eA = __expf(2.0f * (aA0 + aA1));
        const float eB = __expf(2.0f * (aB0 + aB1));
        const float pA = eA + 1.0f, pB = eB + 1.0f;
        const float r  = __builtin_amdgcn_rcpf(pA * pB);
        const float hnA = fmaf(-2.0f * pB, r, 1.0f);
        const float hnB = fmaf(-2.0f * pA, r, 1.0f);
        if (sel != 0) { hoA = hnA; hoB = hnB; }      // Keras masking: carry h

        outA[(TB + u) * RR] = hoA;                   // imm offsets <= 3920B
        outB[(TB + u) * RR] = hoB;
    }
}

// =============== K1: recurrence + LINEAR logit epilogue ===============
// R23 = R20's K1 + per-step logit compute/store (zero trans added).
// K2 shrinks from a 104MB pass to a 39MB in-place softmax.
__global__ __launch_bounds__(256, 2)
void rnn_seq_kernel(const int* __restrict__ tok_ids,
                    const float* __restrict__ labels,
                    const float* __restrict__ emb,
                    const float* __restrict__ W,
                    const float* __restrict__ U,
                    const float* __restrict__ bvec,
                    const float* __restrict__ Wo,
                    const float* __restrict__ bo,
                    float* __restrict__ states_out,
                    float* __restrict__ logits_out)
{
    __shared__ unsigned char s_code[4][8 * 100];  // (sel<<2)|y per (row,t)

    const int tid = threadIdx.x;
    const int w   = tid >> 6;
    const int l   = tid & 63;
    const int r8  = l >> 3;                   // row within wave (0..7)
    const int g   = l & 7;                    // unit slot (0..7)
    const int rowbase = blockIdx.x * 32 + w * 8;

    // ---- preamble: classify tokens+labels -> code bytes (coalesced) ----
#pragma unroll
    for (int i = 0; i < 13; ++i) {
        const int p = l + 64 * i;
        if (p < 8 * TT) {
            const size_t gi = (size_t)rowbase * TT + p;
            const int   tk  = tok_ids[gi];
            const float la1 = labels[gi * LL + 1];
            const float la2 = labels[gi * LL + 2];
            const int   y   = (la1 > 0.5f) ? 1 : ((la2 > 0.5f) ? 2 : 0);
            const int   r   = p / TT;         // compile-time divisor
            s_code[w][r * 100 + (p - r * TT)] = (unsigned char)((tk << 2) | y);
        }
    }

    // ---- pack own row: sel at slot t, y at slot t+1 (pipeline skew) ----
    const unsigned char* cp = &s_code[w][r8 * 100];
    uint64_t sw0 = 0, sw1 = 0, sw2 = 0, sw3 = 0;
    uint64_t yw0 = 0, yw1 = 0, yw2 = 0, yw3 = 0;
#pragma unroll
    for (int t = 0; t < TT; ++t) {
        const uint64_t c  = (uint64_t)cp[t];
        const uint64_t sv = (c >> 2) & 3, yv = c & 3;
        if (t < 32)              sw0 |= sv << (2 * t);
        else if (t < 64)         sw1 |= sv << (2 * (t - 32));
        else if (t < 96)         sw2 |= sv << (2 * (t - 64));
        else                     sw3 |= sv << (2 * (t - 96));
        const int s2 = t + 1;
        if (s2 < 32)             yw0 |= yv << (2 * s2);
        else if (s2 < 64)        yw1 |= yv << (2 * (s2 - 32));
        else if (s2 < 96)        yw2 |= yv << (2 * (s2 - 64));
        else                     yw3 |= yv << (2 * (s2 - 96));
    }
    const int y98 = (int)((yw3 >> 6) & 3);    // slot 99 = step 98

    // ---- per-lane gather order (quad-dependent) + weight coefficients ----
    const int qpar = g >> 2;
    int ord[8];
#pragma unroll
    for (int j = 0; j < 4; ++j) {
        ord[j]     = qpar ? 4 + j : j;
        ord[4 + j] = qpar ? 3 - j : 7 - j;
    }
    const int jA = g;
    const int jB = ((g & 3) < 2) ? 8 + (g & 3) : 8;
    const int gc = ((g & 3) < 2) ? (g & 3) : 2;    // this lane's logit class

    float UA[RR], UB[RR], Wc[RR];
#pragma unroll
    for (int k2 = 0; k2 < 8; ++k2) {
        UA[k2] = U[ord[k2] * RR + jA];
        UB[k2] = U[ord[k2] * RR + jB];
        Wc[k2] = Wo[ord[k2] * LL + gc];            // same permutation as hg
    }
    UA[8] = U[8 * RR + jA]; UA[9] = U[9 * RR + jA];
    UB[8] = U[8 * RR + jB]; UB[9] = U[9 * RR + jB];
    Wc[8] = Wo[8 * LL + gc]; Wc[9] = Wo[9 * LL + gc];
    const float boc = bo[gc];

    float cA1 = bvec[jA], cA2 = cA1, cB1 = bvec[jB], cB2 = cB1;
#pragma unroll
    for (int i = 0; i < RR; ++i) {
        const float e1 = emb[RR + i];          // token-1 row
        const float e2 = emb[2 * RR + i];      // token-2 row
        const float wA = W[i * RR + jA];
        const float wB = W[i * RR + jB];
        cA1 = fmaf(e1, wA, cA1); cA2 = fmaf(e2, wA, cA2);
        cB1 = fmaf(e1, wB, cB1); cB2 = fmaf(e2, wB, cB2);
    }

    const int row = rowbase + r8;
    float* outA = states_out + (size_t)row * (TT * RR) + jA;
    float* outB = states_out + (size_t)row * (TT * RR) + jB;
    float* prow = logits_out + (size_t)row * (TT * LL);

    float hoA = 0.0f, hoB = 0.0f;

    rnn_section< 0, 32>(sw0, yw0, hoA, hoB, UA, UB, Wc, boc,
                        cA1, cA2, cB1, cB2, outA, outB, prow, g);
    rnn_section<32, 32>(sw1, yw1, hoA, hoB, UA, UB, Wc, boc,
                        cA1, cA2, cB1, cB2, outA, outB, prow, g);
    rnn_section<64, 32>(sw2, yw2, hoA, hoB, UA, UB, Wc, boc,
                        cA1, cA2, cB1, cB2, outA, outB, prow, g);
    rnn_section<96,  3>(sw3, yw3, hoA, hoB, UA, UB, Wc, boc,
                        cA1, cA2, cB1, cB2, outA, outB, prow, g);

    // ---- final logits for step 98 (h_98 is in hoA/hoB) ----
    {
        float hg[RR];
        gather10(hoA, hoB, hg);
        logit_step(hg, y98, 98, g, Wc, boc, prow);
    }
}

// ========== K2: in-place softmax over logits + loss/acc partials ==========
// Each thread owns one (b,t): reads its 3 logits (y in l0's low bits),
// softmaxes IN PLACE, accumulates loss/acc. 39MB traffic, full occupancy.
__global__ __launch_bounds__(256)
void softmax_kernel(float* __restrict__ probs,        // in: logits, out: probs
                    float* __restrict__ ws)
{
    const int NT     = BB * TT;               // 1,622,016
    const int tid    = blockIdx.x * 256 + threadIdx.x;
    const int stride = 2048 * 256;

    float loss = 0.0f;
    int   corr = 0;

#pragma unroll 1
    for (int idx = tid; idx < NT; idx += stride) {
        float* pp = probs + (size_t)idx * LL;
        const float l0 = pp[0], l1 = pp[1], l2 = pp[2];
        const int   y  = __float_as_int(l0) & 3;

        const float e0 = __expf(l0), e1 = __expf(l1), e2 = __expf(l2);
        const float S  = e0 + e1 + e2;
        const float rs = __builtin_amdgcn_rcpf(S);
        pp[0] = e0 * rs; pp[1] = e1 * rs; pp[2] = e2 * rs;

        // loss: -log(clip(p_y, 1e-7, 1)) == min(logS - l_y, -log(1e-7))
        const float ly = (y == 0) ? l0 : ((y == 1) ? l1 : l2);
        loss += fminf(__logf(S) - ly, 16.11809565f);

        // accuracy: argmax(logits) == argmax(probs) (monotonic, same ties)
        int ap = 0; float pm = l0;
        if (l1 > pm) { ap = 1; pm = l1; }
        if (l2 > pm) { ap = 2; }
        corr += (ap == y) ? 1 : 0;
    }

    __shared__ float sl[4], sc[4];
    float ls = loss, cs = (float)corr;
#pragma unroll
    for (int off = 32; off > 0; off >>= 1) {
        ls += __shfl_down(ls, off, 64);
        cs += __shfl_down(cs, off, 64);
    }
    if ((threadIdx.x & 63) == 0) { sl[threadIdx.x >> 6] = ls; sc[threadIdx.x >> 6] = cs; }
    __syncthreads();
    if (threadIdx.x == 0) {
        ws[blockIdx.x]        = sl[0] + sl[1] + sl[2] + sl[3];
        ws[2048 + blockIdx.x] = sc[0] + sc[1] + sc[2] + sc[3];
    }
}

__global__ __launch_bounds__(256)
void finalize_kernel(const float* __restrict__ ws, float* __restrict__ out_tail)
{
    __shared__ float sl[4], sc[4];
    const int t = threadIdx.x;
    float ls = 0.0f, cs = 0.0f;
#pragma unroll
    for (int i = 0; i < 8; ++i) {
        ls += ws[t + 256 * i];
        cs += ws[2048 + t + 256 * i];
    }
#pragma unroll
    for (int off = 32; off > 0; off >>= 1) {
        ls += __shfl_down(ls, off, 64);
        cs += __shfl_down(cs, off, 64);
    }
    if ((t & 63) == 0) { sl[t >> 6] = ls; sc[t >> 6] = cs; }
    __syncthreads();
    if (t == 0) {
        const float L = sl[0] + sl[1] + sl[2] + sl[3];
        const float C = sc[0] + sc[1] + sc[2] + sc[3];
        const float inv = 1.0f / (float)((size_t)BB * TT);
        out_tail[0] = C * inv;   // accuracy
        out_tail[1] = L * inv;   // loss
    }
}

extern "C" void kernel_launch(void* const* d_in, const int* in_sizes, int n_in,
                              void* d_out, int out_size, void* d_ws, size_t ws_size,
                              hipStream_t stream)
{
    const int*   tok    = (const int*)  d_in[0];
    const float* labels = (const float*)d_in[1];
    // d_in[2] = mask (unused by reference math)
    const float* emb = (const float*)d_in[3];
    const float* W   = (const float*)d_in[4];
    const float* U   = (const float*)d_in[5];
    const float* bv  = (const float*)d_in[6];
    const float* Wo  = (const float*)d_in[7];
    const float* bo  = (const float*)d_in[8];

    float* out    = (float*)d_out;
    float* states = out;                                  // [B,T,10]
    float* probs  = out + (size_t)BB * TT * RR;           // [B,T,3] (logits first)
    float* tail   = out + (size_t)BB * TT * (RR + LL);    // accuracy, loss
    float* ws     = (float*)d_ws;                         // 4096 floats used

    rnn_seq_kernel<<<BB / 32, 256, 0, stream>>>(tok, labels, emb, W, U, bv,
                                                Wo, bo, states, probs);
    softmax_kernel<<<2048, 256, 0, stream>>>(probs, ws);
    finalize_kernel<<<1, 256, 0, stream>>>(ws, tail);
}

// Round 24
// 52.288 us; speedup vs baseline: 1.2367x; 1.0133x over previous
//
#include <hip/hip_runtime.h>
#include <math.h>

// Problem constants
#define BB 16384
#define TT 99
#define RR 10
#define LL 3

// DPP cross-lane (VALU pipe):
// QP(v,j): every lane of a 4-lane quad gets quad-lane j's value.
// HMIR(v): mirror within each 8-lane half-row (lane g <-> 7-g).
#define QP(v, j) __int_as_float(__builtin_amdgcn_mov_dpp(                     \
    __float_as_int(v), (j) * 0x55, 0xF, 0xF, true))
#define HMIR(v)  __int_as_float(__builtin_amdgcn_mov_dpp(                     \
    __float_as_int(v), 0x141, 0xF, 0xF, true))

// 8-lane full-h gather: 11 DPP ops (verified R15+).
__device__ __forceinline__ void gather10(float hoA, float hoB, float (&hg)[RR]) {
    hg[0] = QP(hoA, 0); hg[1] = QP(hoA, 1);
    hg[2] = QP(hoA, 2); hg[3] = QP(hoA, 3);
    const float mr = HMIR(hoA);
    hg[4] = QP(mr, 0);  hg[5] = QP(mr, 1);
    hg[6] = QP(mr, 2);  hg[7] = QP(mr, 3);
    hg[8] = QP(hoB, 0); hg[9] = QP(hoB, 1);
}

// Linear logit step: ONE logit per lane (10 FMA, zero trans). Lane 0 embeds
// label class y in l0's low 2 mantissa bits (<=2ulp vs 0.022 threshold).
// R24 FIX vs R23: logits go to LDS (1 predicated ds_write, conflict-free)
// instead of a per-step scattered global store (8x12B segments/instr was
// ~+25us on K1). Flushed coalesced once at kernel end.
__device__ __forceinline__ void logit_step(
    const float (&hg)[RR], int yv, int tep, int g,
    const float (&Wc)[RR], float boc, float* __restrict__ srow)
{
    float lg = boc;
#pragma unroll
    for (int i = 0; i < RR; ++i) lg = fmaf(hg[i], Wc[i], lg);
    if (g == 0) lg = __int_as_float((__float_as_int(lg) & ~3) | yv);
    if (g < 3) srow[tep * LL + g] = lg;        // imm-offset ds_write
}

// One section of the recurrence, fully unrolled; all offsets compile-time.
// PIPELINE SKEW (verified R22/R23): iteration t's gather (h_{t-1}) feeds the
// logits for step t-1; y-packs slot-shifted +1.
template <int TB, int N>
__device__ __forceinline__ void rnn_section(
    uint64_t wsel, uint64_t wy, float& hoA, float& hoB,
    const float (&UA)[RR], const float (&UB)[RR],
    const float (&Wc)[RR], float boc,
    float cA1, float cA2, float cB1, float cB2,
    float* __restrict__ outA, float* __restrict__ outB,
    float* __restrict__ srow, int g)
{
#pragma unroll
    for (int u = 0; u < N; ++u) {
        const int sel = (int)(wsel & 3); wsel >>= 2;
        const int yv  = (int)(wy & 3);   wy >>= 2;   // y for step TB+u-1

        float hg[RR];
        gather10(hoA, hoB, hg);                      // h_{t-1}

        if (TB + u > 0)                              // folds at unroll time
            logit_step(hg, yv, TB + u - 1, g, Wc, boc, srow);

        const bool is1 = (sel == 1);
        float aA0 = is1 ? cA1 : cA2, aB0 = is1 ? cB1 : cB2;
        float aA1 = 0.0f, aB1 = 0.0f;
#pragma unroll
        for (int i = 0; i < 5; ++i) {                // split chains: 2x5 deep
            aA0 = fmaf(hg[i],     UA[i],     aA0);
            aA1 = fmaf(hg[5 + i], UA[5 + i], aA1);
            aB0 = fmaf(hg[i],     UB[i],     aB0);
            aB1 = fmaf(hg[5 + i], UB[5 + i], aB1);
        }
        // tanh pair, shared rcp (3 trans)
        const float eA = __expf(2.0f * (aA0 + aA1));
        const float eB = __expf(2.0f * (aB0 + aB1));
        const float pA = eA + 1.0f, pB = eB + 1.0f;
        const float r  = __builtin_amdgcn_rcpf(pA * pB);
        const float hnA = fmaf(-2.0f * pB, r, 1.0f);
        const float hnB = fmaf(-2.0f * pA, r, 1.0f);
        if (sel != 0) { hoA = hnA; hoB = hnB; }      // Keras masking: carry h

        outA[(TB + u) * RR] = hoA;                   // imm offsets <= 3920B
        if (g < 2) outB[(TB + u) * RR] = hoB;        // only true owners (R24)
    }
}

// =============== K1: recurrence + linear logits (LDS-staged) ===============
__global__ __launch_bounds__(256, 2)
void rnn_seq_kernel(const int* __restrict__ tok_ids,
                    const float* __restrict__ labels,
                    const float* __restrict__ emb,
                    const float* __restrict__ W,
                    const float* __restrict__ U,
                    const float* __restrict__ bvec,
                    const float* __restrict__ Wo,
                    const float* __restrict__ bo,
                    float* __restrict__ states_out,
                    float* __restrict__ logits_out)
{
    __shared__ __align__(16) float   s_lg[4][8 * TT * LL];   // 38,016 B
    __shared__ unsigned char         s_code[4][8 * 100];     //  3,200 B

    const int tid = threadIdx.x;
    const int w   = tid >> 6;
    const int l   = tid & 63;
    const int r8  = l >> 3;                   // row within wave (0..7)
    const int g   = l & 7;                    // unit slot (0..7)
    const int rowbase = blockIdx.x * 32 + w * 8;

    // ---- preamble: classify tokens+labels -> code bytes (coalesced) ----
#pragma unroll
    for (int i = 0; i < 13; ++i) {
        const int p = l + 64 * i;
        if (p < 8 * TT) {
            const size_t gi = (size_t)rowbase * TT + p;
            const int   tk  = tok_ids[gi];
            const float la1 = labels[gi * LL + 1];
            const float la2 = labels[gi * LL + 2];
            const int   y   = (la1 > 0.5f) ? 1 : ((la2 > 0.5f) ? 2 : 0);
            const int   r   = p / TT;         // compile-time divisor
            s_code[w][r * 100 + (p - r * TT)] = (unsigned char)((tk << 2) | y);
        }
    }

    // ---- pack own row: sel at slot t, y at slot t+1 (pipeline skew) ----
    const unsigned char* cp = &s_code[w][r8 * 100];
    uint64_t sw0 = 0, sw1 = 0, sw2 = 0, sw3 = 0;
    uint64_t yw0 = 0, yw1 = 0, yw2 = 0, yw3 = 0;
#pragma unroll
    for (int t = 0; t < TT; ++t) {
        const uint64_t c  = (uint64_t)cp[t];
        const uint64_t sv = (c >> 2) & 3, yv = c & 3;
        if (t < 32)              sw0 |= sv << (2 * t);
        else if (t < 64)         sw1 |= sv << (2 * (t - 32));
        else if (t < 96)         sw2 |= sv << (2 * (t - 64));
        else                     sw3 |= sv << (2 * (t - 96));
        const int s2 = t + 1;
        if (s2 < 32)             yw0 |= yv << (2 * s2);
        else if (s2 < 64)        yw1 |= yv << (2 * (s2 - 32));
        else if (s2 < 96)        yw2 |= yv << (2 * (s2 - 64));
        else                     yw3 |= yv << (2 * (s2 - 96));
    }
    const int y98 = (int)((yw3 >> 6) & 3);    // slot 99 = step 98

    // ---- per-lane gather order (quad-dependent) + weight coefficients ----
    const int qpar = g >> 2;
    int ord[8];
#pragma unroll
    for (int j = 0; j < 4; ++j) {
        ord[j]     = qpar ? 4 + j : j;
        ord[4 + j] = qpar ? 3 - j : 7 - j;
    }
    const int jA = g;
    const int jB = ((g & 3) < 2) ? 8 + (g & 3) : 8;
    const int gc = ((g & 3) < 2) ? (g & 3) : 2;    // this lane's logit class

    float UA[RR], UB[RR], Wc[RR];
#pragma unroll
    for (int k2 = 0; k2 < 8; ++k2) {
        UA[k2] = U[ord[k2] * RR + jA];
        UB[k2] = U[ord[k2] * RR + jB];
        Wc[k2] = Wo[ord[k2] * LL + gc];            // same permutation as hg
    }
    UA[8] = U[8 * RR + jA]; UA[9] = U[9 * RR + jA];
    UB[8] = U[8 * RR + jB]; UB[9] = U[9 * RR + jB];
    Wc[8] = Wo[8 * LL + gc]; Wc[9] = Wo[9 * LL + gc];
    const float boc = bo[gc];

    float cA1 = bvec[jA], cA2 = cA1, cB1 = bvec[jB], cB2 = cB1;
#pragma unroll
    for (int i = 0; i < RR; ++i) {
        const float e1 = emb[RR + i];          // token-1 row
        const float e2 = emb[2 * RR + i];      // token-2 row
        const float wA = W[i * RR + jA];
        const float wB = W[i * RR + jB];
        cA1 = fmaf(e1, wA, cA1); cA2 = fmaf(e2, wA, cA2);
        cB1 = fmaf(e1, wB, cB1); cB2 = fmaf(e2, wB, cB2);
    }

    const int row = rowbase + r8;
    float* outA = states_out + (size_t)row * (TT * RR) + jA;
    float* outB = states_out + (size_t)row * (TT * RR) + jB;
    float* srow = &s_lg[w][r8 * (TT * LL)];   // this row's logit slice

    float hoA = 0.0f, hoB = 0.0f;

    rnn_section< 0, 32>(sw0, yw0, hoA, hoB, UA, UB, Wc, boc,
                        cA1, cA2, cB1, cB2, outA, outB, srow, g);
    rnn_section<32, 32>(sw1, yw1, hoA, hoB, UA, UB, Wc, boc,
                        cA1, cA2, cB1, cB2, outA, outB, srow, g);
    rnn_section<64, 32>(sw2, yw2, hoA, hoB, UA, UB, Wc, boc,
                        cA1, cA2, cB1, cB2, outA, outB, srow, g);
    rnn_section<96,  3>(sw3, yw3, hoA, hoB, UA, UB, Wc, boc,
                        cA1, cA2, cB1, cB2, outA, outB, srow, g);

    // ---- final logits for step 98 (h_98 is in hoA/hoB) ----
    {
        float hg[RR];
        gather10(hoA, hoB, hg);
        logit_step(hg, y98, 98, g, Wc, boc, srow);
    }

    // ---- flush logits: 8 rows x 297 floats = 2376 floats, CONTIGUOUS in
    // both LDS and global (rows adjacent) -> 594 float4, fully coalesced.
    // Same-wave DS ordering: no barrier needed. ----
    {
        const float4* s4 = reinterpret_cast<const float4*>(&s_lg[w][0]);
        float4* d4 = reinterpret_cast<float4*>(
            logits_out + (size_t)rowbase * (TT * LL));
#pragma unroll
        for (int i = 0; i < 10; ++i) {
            const int q = l + 64 * i;
            if (q < 594) d4[q] = s4[q];
        }
    }
}

// ========== K2: in-place softmax over logits + loss/acc partials ==========
__global__ __launch_bounds__(256)
void softmax_kernel(float* __restrict__ probs,        // in: logits, out: probs
                    float* __restrict__ ws)
{
    const int NT     = BB * TT;               // 1,622,016
    const int tid    = blockIdx.x * 256 + threadIdx.x;
    const int stride = 2048 * 256;

    float loss = 0.0f;
    int   corr = 0;

#pragma unroll 1
    for (int idx = tid; idx < NT; idx += stride) {
        float* pp = probs + (size_t)idx * LL;
        const float l0 = pp[0], l1 = pp[1], l2 = pp[2];
        const int   y  = __float_as_int(l0) & 3;

        const float e0 = __expf(l0), e1 = __expf(l1), e2 = __expf(l2);
        const float S  = e0 + e1 + e2;
        const float rs = __builtin_amdgcn_rcpf(S);
        pp[0] = e0 * rs; pp[1] = e1 * rs; pp[2] = e2 * rs;

        // loss: -log(clip(p_y, 1e-7, 1)) == min(logS - l_y, -log(1e-7))
        const float ly = (y == 0) ? l0 : ((y == 1) ? l1 : l2);
        loss += fminf(__logf(S) - ly, 16.11809565f);

        // accuracy: argmax(logits) == argmax(probs) (monotonic, same ties)
        int ap = 0; float pm = l0;
        if (l1 > pm) { ap = 1; pm = l1; }
        if (l2 > pm) { ap = 2; }
        corr += (ap == y) ? 1 : 0;
    }

    __shared__ float sl[4], sc[4];
    float ls = loss, cs = (float)corr;
#pragma unroll
    for (int off = 32; off > 0; off >>= 1) {
        ls += __shfl_down(ls, off, 64);
        cs += __shfl_down(cs, off, 64);
    }
    if ((threadIdx.x & 63) == 0) { sl[threadIdx.x >> 6] = ls; sc[threadIdx.x >> 6] = cs; }
    __syncthreads();
    if (threadIdx.x == 0) {
        ws[blockIdx.x]        = sl[0] + sl[1] + sl[2] + sl[3];
        ws[2048 + blockIdx.x] = sc[0] + sc[1] + sc[2] + sc[3];
    }
}

__global__ __launch_bounds__(256)
void finalize_kernel(const float* __restrict__ ws, float* __restrict__ out_tail)
{
    __shared__ float sl[4], sc[4];
    const int t = threadIdx.x;
    float ls = 0.0f, cs = 0.0f;
#pragma unroll
    for (int i = 0; i < 8; ++i) {
        ls += ws[t + 256 * i];
        cs += ws[2048 + t + 256 * i];
    }
#pragma unroll
    for (int off = 32; off > 0; off >>= 1) {
        ls += __shfl_down(ls, off, 64);
        cs += __shfl_down(cs, off, 64);
    }
    if ((t & 63) == 0) { sl[t >> 6] = ls; sc[t >> 6] = cs; }
    __syncthreads();
    if (t == 0) {
        const float L = sl[0] + sl[1] + sl[2] + sl[3];
        const float C = sc[0] + sc[1] + sc[2] + sc[3];
        const float inv = 1.0f / (float)((size_t)BB * TT);
        out_tail[0] = C * inv;   // accuracy
        out_tail[1] = L * inv;   // loss
    }
}

extern "C" void kernel_launch(void* const* d_in, const int* in_sizes, int n_in,
                              void* d_out, int out_size, void* d_ws, size_t ws_size,
                              hipStream_t stream)
{
    const int*   tok    = (const int*)  d_in[0];
    const float* labels = (const float*)d_in[1];
    // d_in[2] = mask (unused by reference math)
    const float* emb = (const float*)d_in[3];
    const float* W   = (const float*)d_in[4];
    const float* U   = (const float*)d_in[5];
    const float* bv  = (const float*)d_in[6];
    const float* Wo  = (const float*)d_in[7];
    const float* bo  = (const float*)d_in[8];

    float* out    = (float*)d_out;
    float* states = out;                                  // [B,T,10]
    float* probs  = out + (size_t)BB * TT * RR;           // [B,T,3] (logits first)
    float* tail   = out + (size_t)BB * TT * (RR + LL);    // accuracy, loss
    float* ws     = (float*)d_ws;                         // 4096 floats used

    rnn_seq_kernel<<<BB / 32, 256, 0, stream>>>(tok, labels, emb, W, U, bv,
                                                Wo, bo, states, probs);
    softmax_kernel<<<2048, 256, 0, stream>>>(probs, ws);
    finalize_kernel<<<1, 256, 0, stream>>>(ws, tail);
}